// Round 1
// baseline (467.545 us; speedup 1.0000x reference)
//
#include <hip/hip_runtime.h>

typedef short bf16x8 __attribute__((ext_vector_type(8)));
typedef float f32x4 __attribute__((ext_vector_type(4)));

__device__ __forceinline__ ushort f2bf(float f) {
    union { float f; unsigned u; } v; v.f = f;
    unsigned r = (v.u + 0x7fffu + ((v.u >> 16) & 1u)) >> 16;
    return (ushort)r;
}

// ---------------- fp32 -> bf16 conversion ----------------
__global__ __launch_bounds__(256)
void cvt_f32_bf16(const float* __restrict__ src, ushort* __restrict__ dst, int n) {
    int i = (blockIdx.x * 256 + threadIdx.x) * 4;
    if (i >= n) return;
    float4 v = *(const float4*)(src + i);
    ushort4 o;
    o.x = f2bf(v.x); o.y = f2bf(v.y); o.z = f2bf(v.z); o.w = f2bf(v.w);
    *(ushort4*)(dst + i) = o;
}

// ---------------- C[m][n] = sum_k A[m][k] * B[n][k], bf16 in/out, fp32 acc ----
// 128x128 tile, BK=32, 4 waves (2x2) of 64x64 each, mfma 16x16x32 bf16.
__global__ __launch_bounds__(256, 2)
void gemm_bt(const ushort* __restrict__ A, const ushort* __restrict__ B,
             ushort* __restrict__ C, int M, int N, int K)
{
    __shared__ ushort As[128][40];  // 32 k elems + 8 pad (row stride 80B, 16B aligned)
    __shared__ ushort Bs[128][40];
    const int tid = threadIdx.x;
    const int lane = tid & 63, wave = tid >> 6;
    const int wm = wave >> 1, wn = wave & 1;
    const int lr = lane & 15, lq = lane >> 4;
    const int mBase = blockIdx.y * 128, nBase = blockIdx.x * 128;

    f32x4 acc[4][4];
    #pragma unroll
    for (int i = 0; i < 4; ++i)
        #pragma unroll
        for (int j = 0; j < 4; ++j) acc[i][j] = (f32x4){0.f, 0.f, 0.f, 0.f};

    for (int k0 = 0; k0 < K; k0 += 32) {
        __syncthreads();
        // stage 128 rows x 64B for both A and B (2 rounds of 4KB each)
        #pragma unroll
        for (int i = 0; i < 2; ++i) {
            int off = i * 4096 + tid * 16;
            int row = off >> 6, col = off & 63;
            *(uint4*)((char*)As + row * 80 + col) =
                *(const uint4*)((const char*)A + ((size_t)(mBase + row) * K + k0) * 2 + col);
            *(uint4*)((char*)Bs + row * 80 + col) =
                *(const uint4*)((const char*)B + ((size_t)(nBase + row) * K + k0) * 2 + col);
        }
        __syncthreads();
        bf16x8 af[4], bfr[4];
        #pragma unroll
        for (int mi = 0; mi < 4; ++mi) af[mi] = *(const bf16x8*)&As[wm * 64 + mi * 16 + lr][lq * 8];
        #pragma unroll
        for (int ni = 0; ni < 4; ++ni) bfr[ni] = *(const bf16x8*)&Bs[wn * 64 + ni * 16 + lr][lq * 8];
        #pragma unroll
        for (int mi = 0; mi < 4; ++mi)
            #pragma unroll
            for (int ni = 0; ni < 4; ++ni)
                acc[mi][ni] = __builtin_amdgcn_mfma_f32_16x16x32_bf16(af[mi], bfr[ni], acc[mi][ni], 0, 0, 0);
    }
    // C/D layout: col = lane&15, row = (lane>>4)*4 + r
    #pragma unroll
    for (int mi = 0; mi < 4; ++mi)
        #pragma unroll
        for (int ni = 0; ni < 4; ++ni)
            #pragma unroll
            for (int r = 0; r < 4; ++r) {
                int m = mBase + wm * 64 + mi * 16 + lq * 4 + r;
                int n = nBase + wn * 64 + ni * 16 + lr;
                C[(size_t)m * N + n] = f2bf(acc[mi][ni][r]);
            }
}

// ---------------- flash attention ----------------
// Q,K: [B*S, 512] bf16 row-major. Vt: [512, B*S] bf16 (row stride 16384).
// Grid (32, 8): 64 Q-rows per block, wave w owns rows [16w,16w+16). K-tile = 32 keys.
__global__ __launch_bounds__(256, 1)
void attn_kernel(const ushort* __restrict__ Qg, const ushort* __restrict__ Kg,
                 const ushort* __restrict__ Vtg, const int* __restrict__ maskg,
                 float* __restrict__ Outg)
{
    const int S = 2048, D = 512;
    const float SL2E = 0.0637587160f;  // (1/sqrt(512)) * log2(e)

    __shared__ ushort Ks[32][520];   // 32 keys x 512 d (+8 pad)   33280 B
    __shared__ ushort Vs[256][40];   // 256 d   x 32 keys (+8 pad) 20480 B
    __shared__ ushort Ps[4][16][40]; // per-wave P 16x32 (+8 pad)   5120 B

    const int b = blockIdx.y, qt = blockIdx.x;
    const int tid = threadIdx.x, lane = tid & 63, wave = tid >> 6;
    const int lr = lane & 15, lq = lane >> 4;

    // resident Q fragments: A-layout row = lane&15, k = (lane>>4)*8 + j
    const ushort* Qp = Qg + ((size_t)b * S + qt * 64 + wave * 16 + lr) * D;
    bf16x8 qf[16];
    #pragma unroll
    for (int c = 0; c < 16; ++c) qf[c] = *(const bf16x8*)(Qp + c * 32 + lq * 8);

    f32x4 o[32];
    #pragma unroll
    for (int i = 0; i < 32; ++i) o[i] = (f32x4){0.f, 0.f, 0.f, 0.f};
    float m_i[4] = {-1e30f, -1e30f, -1e30f, -1e30f};
    float l_i[4] = {0.f, 0.f, 0.f, 0.f};

    const char* Kbase = (const char*)(Kg + (size_t)b * S * D);
    const char* Vbase = (const char*)(Vtg + (size_t)b * 2048);
    const int* mrow = maskg + b * S;

    for (int kt = 0; kt < 64; ++kt) {
        const int key0 = kt * 32;
        __syncthreads();
        {   // stage K tile: 32 keys x 1024 B (coalesced 16B/lane)
            const char* gK = Kbase + (size_t)key0 * 1024;
            #pragma unroll
            for (int i = 0; i < 8; ++i) {
                int off = i * 4096 + tid * 16;
                int row = off >> 10, col = off & 1023;
                *(uint4*)((char*)Ks + row * 1040 + col) =
                    *(const uint4*)(gK + (size_t)row * 1024 + col);
            }
            // stage V chunk 0: d 0..255, 64 B per d-row
            const char* gV = Vbase + (size_t)key0 * 2;
            #pragma unroll
            for (int i = 0; i < 4; ++i) {
                int off = i * 4096 + tid * 16;
                int row = off >> 6, col = off & 63;
                *(uint4*)((char*)Vs + row * 80 + col) =
                    *(const uint4*)(gV + (size_t)row * 32768 + col);
            }
        }
        __syncthreads();
        // S = Q Ktile^T : both operands use the row-major "B^T" frag pattern
        f32x4 sf0 = (f32x4){0.f,0.f,0.f,0.f}, sf1 = (f32x4){0.f,0.f,0.f,0.f};
        #pragma unroll
        for (int ks = 0; ks < 16; ++ks) {
            bf16x8 kf0 = *(const bf16x8*)&Ks[lr][ks * 32 + lq * 8];
            bf16x8 kf1 = *(const bf16x8*)&Ks[16 + lr][ks * 32 + lq * 8];
            sf0 = __builtin_amdgcn_mfma_f32_16x16x32_bf16(qf[ks], kf0, sf0, 0, 0, 0);
            sf1 = __builtin_amdgcn_mfma_f32_16x16x32_bf16(qf[ks], kf1, sf1, 0, 0, 0);
        }
        // online softmax (log2 domain). C-layout: col(key)=lane&15, row=lq*4+r.
        const bool msk0 = mrow[key0 + lr] != 0;
        const bool msk1 = mrow[key0 + 16 + lr] != 0;
        float t0[4], t1[4], rmax[4];
        #pragma unroll
        for (int r = 0; r < 4; ++r) {
            t0[r] = msk0 ? -1e30f : sf0[r] * SL2E;
            t1[r] = msk1 ? -1e30f : sf1[r] * SL2E;
            rmax[r] = fmaxf(t0[r], t1[r]);
        }
        #pragma unroll
        for (int r = 0; r < 4; ++r)
            #pragma unroll
            for (int off = 1; off < 16; off <<= 1)
                rmax[r] = fmaxf(rmax[r], __shfl_xor(rmax[r], off, 16));
        float alpha[4], p0[4], p1[4], psum[4];
        #pragma unroll
        for (int r = 0; r < 4; ++r) {
            float mn = fmaxf(m_i[r], rmax[r]);
            alpha[r] = exp2f(m_i[r] - mn);
            m_i[r] = mn;
            p0[r] = exp2f(t0[r] - mn);
            p1[r] = exp2f(t1[r] - mn);
            psum[r] = p0[r] + p1[r];
        }
        #pragma unroll
        for (int r = 0; r < 4; ++r) {
            #pragma unroll
            for (int off = 1; off < 16; off <<= 1)
                psum[r] += __shfl_xor(psum[r], off, 16);
            l_i[r] = l_i[r] * alpha[r] + psum[r];
        }
        // P: C-layout -> LDS -> A-layout (wave-private buffer)
        #pragma unroll
        for (int r = 0; r < 4; ++r) {
            Ps[wave][lq * 4 + r][lr]      = f2bf(p0[r]);
            Ps[wave][lq * 4 + r][16 + lr] = f2bf(p1[r]);
        }
        #pragma unroll
        for (int i = 0; i < 32; ++i) {
            o[i][0] *= alpha[0]; o[i][1] *= alpha[1];
            o[i][2] *= alpha[2]; o[i][3] *= alpha[3];
        }
        bf16x8 pf = *(const bf16x8*)&Ps[wave][lr][lq * 8];
        // O += P @ Vt-chunk0 (d 0..255)
        #pragma unroll
        for (int db = 0; db < 16; ++db) {
            bf16x8 vf = *(const bf16x8*)&Vs[db * 16 + lr][lq * 8];
            o[db] = __builtin_amdgcn_mfma_f32_16x16x32_bf16(pf, vf, o[db], 0, 0, 0);
        }
        __syncthreads();
        {   // stage V chunk 1: d 256..511
            const char* gV = Vbase + (size_t)256 * 32768 + (size_t)key0 * 2;
            #pragma unroll
            for (int i = 0; i < 4; ++i) {
                int off = i * 4096 + tid * 16;
                int row = off >> 6, col = off & 63;
                *(uint4*)((char*)Vs + row * 80 + col) =
                    *(const uint4*)(gV + (size_t)row * 32768 + col);
            }
        }
        __syncthreads();
        #pragma unroll
        for (int db = 0; db < 16; ++db) {
            bf16x8 vf = *(const bf16x8*)&Vs[db * 16 + lr][lq * 8];
            o[16 + db] = __builtin_amdgcn_mfma_f32_16x16x32_bf16(pf, vf, o[16 + db], 0, 0, 0);
        }
    }
    float inv[4];
    #pragma unroll
    for (int r = 0; r < 4; ++r) inv[r] = l_i[r] > 0.f ? 1.f / l_i[r] : 0.f;
    float* Op = Outg + ((size_t)b * S + qt * 64 + wave * 16 + lq * 4) * D;
    #pragma unroll
    for (int db = 0; db < 32; ++db)
        #pragma unroll
        for (int r = 0; r < 4; ++r)
            Op[(size_t)r * D + db * 16 + lr] = o[db][r] * inv[r];
}

extern "C" void kernel_launch(void* const* d_in, const int* in_sizes, int n_in,
                              void* d_out, int out_size, void* d_ws, size_t ws_size,
                              hipStream_t stream) {
    const float* x  = (const float*)d_in[0];
    // d_in[1] = bias: additive scalar on all logits -> softmax shift-invariant -> no-op
    const int* mask = (const int*)d_in[2];
    const float* Wq = (const float*)d_in[3];
    const float* Wk = (const float*)d_in[4];
    const float* Wv = (const float*)d_in[5];
    float* out = (float*)d_out;

    ushort* ws  = (ushort*)d_ws;
    ushort* xb  = ws;               // 16384x512
    ushort* wqb = xb + 8388608;     // 512x512
    ushort* wkb = wqb + 262144;
    ushort* wvb = wkb + 262144;
    ushort* Qb  = wvb + 262144;     // 16384x512
    ushort* Kb  = Qb + 8388608;     // 16384x512
    ushort* Vtb = Kb + 8388608;     // 512x16384 (V transposed, batches along cols)

    cvt_f32_bf16<<<8192, 256, 0, stream>>>(x, xb, 8388608);
    cvt_f32_bf16<<<256, 256, 0, stream>>>(Wq, wqb, 262144);
    cvt_f32_bf16<<<256, 256, 0, stream>>>(Wk, wkb, 262144);
    cvt_f32_bf16<<<256, 256, 0, stream>>>(Wv, wvb, 262144);
    // Q = x Wq^T, K = x Wk^T  (M=16384, N=512, K=512)
    gemm_bt<<<dim3(4, 128), 256, 0, stream>>>(xb, wqb, Qb, 16384, 512, 512);
    gemm_bt<<<dim3(4, 128), 256, 0, stream>>>(xb, wkb, Kb, 16384, 512, 512);
    // Vt = Wv x^T  (M=512, N=16384, K=512) -> V transposed for free
    gemm_bt<<<dim3(128, 4), 256, 0, stream>>>(wvb, xb, Vtb, 512, 16384, 512);
    attn_kernel<<<dim3(32, 8), 256, 0, stream>>>(Qb, Kb, Vtb, mask, out);
}